// Round 7
// baseline (454.033 us; speedup 1.0000x reference)
//
#include <hip/hip_runtime.h>
#include <math.h>

// Round 15:
//  * GEMM core unchanged (m97 structure, proven 806 TF) + T1 XCD-stripe
//    swizzle (each XCD gets a 4-m-row stripe, n-fastest: B-panel L2 reuse).
//  * QKV epilogue writes V DIRECTLY transposed (bh,dh,l) as packed ushort4
//    (C-fragment rows are 4 consecutive l) -> transpose_v kernel deleted.
//  * Attention: parity-packed Ps writes (32 ds_write_b16 -> 16 ds_write_b32
//    via quad_perm DPP neighbor) + defer-max (T13, THR=8, wave-uniform skip
//    of the O-rescale pass).
//  * RoPE+norm and attn core structure unchanged.

#define D 2048
#define NH 16
#define DH 128
#define BB 2
#define LL 2048
#define BHD (BB*NH)      // 32
#define MROWS (BB*LL)    // 4096
#define KDIM D

typedef __attribute__((ext_vector_type(8))) short short8;
typedef __attribute__((ext_vector_type(4))) float floatx4;

// fp32 -> bf16, round-to-nearest-even
__device__ __forceinline__ unsigned short f2bf(float f) {
    unsigned u = __float_as_uint(f);
    unsigned r = u + 0x7FFFu + ((u >> 16) & 1u);
    return (unsigned short)(r >> 16);
}
__device__ __forceinline__ float bf2f(unsigned short u) {
    return __uint_as_float(((unsigned)u) << 16);
}

// async global->LDS DMA (16 B per lane); LDS dest = wave-uniform base + lane*16
__device__ __forceinline__ void async16(const void* g, void* lds) {
    __builtin_amdgcn_global_load_lds(
        (const __attribute__((address_space(1))) unsigned int*)g,
        (__attribute__((address_space(3))) unsigned int*)lds, 16, 0, 0);
}

// DPP lane-moves within 16-lane rows (VALU pipe, avoids ds_bpermute).
template<int CTRL>
__device__ __forceinline__ float dpp_movf(float x) {
    return __int_as_float(__builtin_amdgcn_update_dpp(
        0, __float_as_int(x), CTRL, 0xF, 0xF, true));
}
__device__ __forceinline__ float row_max16(float x) {
    x = fmaxf(x, dpp_movf<0xB1>(x));    // quad_perm xor1
    x = fmaxf(x, dpp_movf<0x4E>(x));    // quad_perm xor2
    x = fmaxf(x, dpp_movf<0x124>(x));   // row_ror:4
    x = fmaxf(x, dpp_movf<0x128>(x));   // row_ror:8
    return x;
}
__device__ __forceinline__ float row_sum16(float x) {
    x += dpp_movf<0xB1>(x);
    x += dpp_movf<0x4E>(x);
    x += dpp_movf<0x124>(x);
    x += dpp_movf<0x128>(x);
    return x;
}

// ---------------------------------------------------------------------------
// elementwise fp32 -> bf16 cast (float4 vectorized)
// ---------------------------------------------------------------------------
__global__ __launch_bounds__(256)
void cast_bf16_r15(const float* __restrict__ in,
                   unsigned short* __restrict__ out, int n4)
{
    int i = blockIdx.x * 256 + threadIdx.x;
    if (i < n4) {
        float4 v = ((const float4*)in)[i];
        ushort4 o;
        o.x = f2bf(v.x); o.y = f2bf(v.y); o.z = f2bf(v.z); o.w = f2bf(v.w);
        ((ushort4*)out)[i] = o;
    }
}

// ---------------------------------------------------------------------------
// W (K x N fp32 row-major) -> Wt (N x K bf16 row-major) via 32x32 LDS tile
// ---------------------------------------------------------------------------
__global__ __launch_bounds__(256)
void transpose_cast_r15(const float* __restrict__ W,
                        unsigned short* __restrict__ Wt, int K, int N)
{
    __shared__ float tile[32][33];
    const int tx = threadIdx.x & 31, ty = threadIdx.x >> 5;  // ty: 0..7
    const int n0 = blockIdx.x * 32, k0 = blockIdx.y * 32;
#pragma unroll
    for (int r = 0; r < 4; r++)
        tile[ty + 8 * r][tx] = W[(size_t)(k0 + ty + 8 * r) * N + n0 + tx];
    __syncthreads();
#pragma unroll
    for (int r = 0; r < 4; r++)
        Wt[(size_t)(n0 + ty + 8 * r) * K + k0 + tx] = f2bf(tile[tx][ty + 8 * r]);
}

// ---------------------------------------------------------------------------
// bf16 MFMA GEMM (m97 structure + XCD stripe swizzle):
// C(MxN) = A(MxK) * Bt(NxK)^T. 128x128 tile, BK=32, 4 waves x 64x64.
// MODE 0: fp32 store to C. MODE 1: bf16 scatter to Q/K (B,H,L,Dh) and V
// written DIRECTLY TRANSPOSED to (bh, dh, l) with packed ushort4 stores.
// ---------------------------------------------------------------------------
template<int N, int MODE>
__global__ __launch_bounds__(256)
void gemm_mfma_r15(const unsigned short* __restrict__ A,
                   const unsigned short* __restrict__ Bt,
                   float* __restrict__ C, unsigned short* __restrict__ Qo,
                   unsigned short* __restrict__ Ko, unsigned short* __restrict__ Vo)
{
    __shared__ unsigned short As[128 * 32];   // [m][k] contiguous (DMA order)
    __shared__ unsigned short Bs[128 * 32];   // [n][k] contiguous
    const int t = threadIdx.x;
    const int w = t >> 6, lane = t & 63;
    const int lrow = lane & 15, quad = lane >> 4;

    // T1: XCD-stripe swizzle. Linear dispatch order round-robins XCDs, so
    // give each XCD (lin&7) a contiguous 4-m-row stripe, iterated n-fastest:
    // B-panel reused 4x back-to-back in that XCD's private L2.
    // Requires gridDim.y % 32 == 0 with gridDim.y=32 here (bijective).
    const int lin = blockIdx.y * gridDim.x + blockIdx.x;
    const int xcd = lin & 7, idx = lin >> 3;
    const int m0 = (xcd * 4 + (idx & 3)) * 128;
    const int n0 = (idx >> 2) * 128;

    const int wm = (w >> 1) * 64, wn = (w & 1) * 64;

    floatx4 acc[4][4];
#pragma unroll
    for (int i = 0; i < 4; i++)
#pragma unroll
        for (int j = 0; j < 4; j++) acc[i][j] = (floatx4){0.f, 0.f, 0.f, 0.f};

    const int srow = 32 * w + (lane >> 2);
    const int sseg = (lane & 3) * 8;

    for (int k0 = 0; k0 < KDIM; k0 += 32) {
        __syncthreads();
        async16(&A [(size_t)(m0 + srow)      * KDIM + k0 + sseg], &As[(32 * w)      * 32]);
        async16(&A [(size_t)(m0 + srow + 16) * KDIM + k0 + sseg], &As[(32 * w + 16) * 32]);
        async16(&Bt[(size_t)(n0 + srow)      * KDIM + k0 + sseg], &Bs[(32 * w)      * 32]);
        async16(&Bt[(size_t)(n0 + srow + 16) * KDIM + k0 + sseg], &Bs[(32 * w + 16) * 32]);
        __syncthreads();

        short8 a[4], b[4];
#pragma unroll
        for (int i = 0; i < 4; i++)
            a[i] = *(const short8*)&As[(wm + i * 16 + lrow) * 32 + quad * 8];
#pragma unroll
        for (int j = 0; j < 4; j++)
            b[j] = *(const short8*)&Bs[(wn + j * 16 + lrow) * 32 + quad * 8];
#pragma unroll
        for (int i = 0; i < 4; i++)
#pragma unroll
            for (int j = 0; j < 4; j++)
                acc[i][j] = __builtin_amdgcn_mfma_f32_16x16x32_bf16(a[i], b[j], acc[i][j], 0, 0, 0);
    }

    // C/D fragment layout: col = lane&15, row = quad*4 + reg (m89-verified)
    if (MODE == 0) {
#pragma unroll
        for (int i = 0; i < 4; i++)
#pragma unroll
            for (int j = 0; j < 4; j++) {
                int col = n0 + wn + j * 16 + lrow;
#pragma unroll
                for (int r = 0; r < 4; r++) {
                    int m = m0 + wm + i * 16 + quad * 4 + r;
                    C[(size_t)m * N + col] = acc[i][j][r];
                }
            }
    } else {
        const int s = n0 >> 11;              // qkv slot (uniform per block)
        const int h = (n0 & 2047) >> 7;
        if (s == 2) {
            // V: write directly transposed (bh, dh, l). The 4 acc regs are
            // 4 consecutive l at fixed dh -> one packed ushort4 store.
#pragma unroll
            for (int i = 0; i < 4; i++) {
                int m = m0 + wm + i * 16 + quad * 4;   // first of 4 l's
                int b = m >> 11, l = m & 2047;
#pragma unroll
                for (int j = 0; j < 4; j++) {
                    int dh = wn + j * 16 + lrow;
                    ushort4 v;
                    v.x = f2bf(acc[i][j][0]); v.y = f2bf(acc[i][j][1]);
                    v.z = f2bf(acc[i][j][2]); v.w = f2bf(acc[i][j][3]);
                    *(ushort4*)&Vo[(((size_t)b * NH + h) * DH + dh) * LL + l] = v;
                }
            }
        } else {
            unsigned short* dst = (s == 0) ? Qo : Ko;
#pragma unroll
            for (int i = 0; i < 4; i++)
#pragma unroll
                for (int j = 0; j < 4; j++) {
                    int dh = wn + j * 16 + lrow;
#pragma unroll
                    for (int r = 0; r < 4; r++) {
                        int m = m0 + wm + i * 16 + quad * 4 + r;
                        int b = m >> 11, l = m & 2047;
                        dst[(((size_t)b * NH + h) * LL + l) * DH + dh] = f2bf(acc[i][j][r]);
                    }
                }
        }
    }
}

// ---------------------------------------------------------------------------
// RoPE + L2-normalize: one 64-lane wave per (bh,l) row, Q and K together.
// Rotate pair (d, d+64) shares cos/sin; zero LDS, zero barriers.
// ---------------------------------------------------------------------------
__global__ __launch_bounds__(256)
void rope_norm_r15(unsigned short* __restrict__ Q,
                   unsigned short* __restrict__ K,
                   const float* __restrict__ s_qk_ptr)
{
    const int wid  = threadIdx.x >> 6;
    const int lane = threadIdx.x & 63;
    const int row  = blockIdx.x * 4 + wid;       // flattened (bh*LL + l)
    const int l    = row & (LL - 1);
    const size_t base = (size_t)row * DH;

    // inv_freq = 10000^(-lane/64); ln(10000)/64 = 0.14391156831
    float ang = (float)l * expf(-0.14391157f * (float)lane);
    float c = cosf(ang), s = sinf(ang);

    float qlo = bf2f(Q[base + lane]), qhi = bf2f(Q[base + lane + 64]);
    float klo = bf2f(K[base + lane]), khi = bf2f(K[base + lane + 64]);

    float qr_lo = fmaf(qlo, c, (-qhi) * s);
    float qr_hi = fmaf(qhi, c,   qlo  * s);
    float kr_lo = fmaf(klo, c, (-khi) * s);
    float kr_hi = fmaf(khi, c,   klo  * s);

    float qs = qr_lo * qr_lo + qr_hi * qr_hi;
    float ks = kr_lo * kr_lo + kr_hi * kr_hi;
    qs = row_sum16(qs);  ks = row_sum16(ks);
    qs += __shfl_xor(qs, 16);  ks += __shfl_xor(ks, 16);
    qs += __shfl_xor(qs, 32);  ks += __shfl_xor(ks, 32);
    float qn = fmaxf(sqrtf(qs), 1e-12f);
    float kn = fmaxf(sqrtf(ks), 1e-12f);

    float sqk = s_qk_ptr[0];
    Q[base + lane]      = f2bf(qr_lo / qn * sqk);
    Q[base + lane + 64] = f2bf(qr_hi / qn * sqk);
    K[base + lane]      = f2bf(kr_lo / kn);
    K[base + lane + 64] = f2bf(kr_hi / kn);
}

// ---------------------------------------------------------------------------
// bf16 MFMA flash attention, causal. BQ=128 per block (4 waves x 32 q-rows),
// BK=64. K/V double-buffered via async DMA with XOR-swizzled layouts; each
// Ks/Vs ds_read_b128 feeds two MFMAs; DPP softmax; 80 KB LDS.
// Round 15: parity-packed Ps writes (even lane = h0 pair, odd = h1 pair,
// neighbor via quad_perm xor1) and defer-max (T13, THR=8).
// ---------------------------------------------------------------------------
#define ABQ 128
#define ABK 64
__global__ __launch_bounds__(256, 2)
void attn_mfma_r15(const unsigned short* __restrict__ Q,
                   const unsigned short* __restrict__ K,
                   const unsigned short* __restrict__ Vt,
                   unsigned short* __restrict__ AOb)
{
    __shared__ __align__(16) unsigned short Ks[2][ABK * DH];   // 32 KB
    __shared__ __align__(16) unsigned short Vs[2][DH * ABK];   // 32 KB
    __shared__ __align__(16) unsigned short Ps[4][32][64];     // 16 KB swizzled

    const int t = threadIdx.x;
    const int w = t >> 6, lane = t & 63;
    const int lrow = lane & 15, quad = lane >> 4;
    const int bh = blockIdx.x;
    const int y  = blockIdx.y;
    const int qt = (y < 8) ? (15 - y) : (y - 8);   // heavy+light pairing
    const int q0 = qt * ABQ;
    const int qw = q0 + w * 32;                    // wave's first q-row

    const unsigned short* Qb = Q  + (size_t)bh * LL * DH;
    const unsigned short* Kb = K  + (size_t)bh * LL * DH;
    const unsigned short* Vg = Vt + (size_t)bh * DH * LL;

    short8 aq[2][4];
#pragma unroll
    for (int h = 0; h < 2; h++)
#pragma unroll
        for (int kk = 0; kk < 4; kk++)
            aq[h][kk] = *(const short8*)&Qb[(size_t)(qw + 16 * h + lrow) * DH
                                            + kk * 32 + quad * 8];

    floatx4 oacc[2][8];
#pragma unroll
    for (int h = 0; h < 2; h++)
#pragma unroll
        for (int dt = 0; dt < 8; dt++) oacc[h][dt] = (floatx4){0.f, 0.f, 0.f, 0.f};
    float mrow[2][4], lsum[2][4];
#pragma unroll
    for (int h = 0; h < 2; h++)
#pragma unroll
        for (int r = 0; r < 4; r++) { mrow[h][r] = -1e30f; lsum[h][r] = 0.f; }

    auto STAGE = [&](int tile, int buf) {
        const int k0s = tile * ABK;
#pragma unroll
        for (int c = 0; c < 4; c++) {
            int row = 16 * w + 4 * c;
            int r   = row + (lane >> 4);
            int col = (lane & 15) ^ (r & 7);
            async16(&Kb[(size_t)(k0s + r) * DH + col * 8], &Ks[buf][row * DH]);
        }
#pragma unroll
        for (int c = 0; c < 4; c++) {
            int row = 32 * w + 8 * c;
            int r   = row + (lane >> 3);
            int col = (lane & 7) ^ (r & 7);
            async16(&Vg[(size_t)r * LL + k0s + col * 8], &Vs[buf][row * ABK]);
        }
    };

    const int ntiles = 2 * qt + 2;
    STAGE(0, 0);
    __syncthreads();

    int cur = 0;
    for (int tile = 0; tile < ntiles; tile++) {
        const int k0 = tile * ABK;
        if (tile + 1 < ntiles) STAGE(tile + 1, cur ^ 1);

        floatx4 sacc[2][4];
#pragma unroll
        for (int h = 0; h < 2; h++)
#pragma unroll
            for (int j = 0; j < 4; j++) sacc[h][j] = (floatx4){0.f, 0.f, 0.f, 0.f};
        __builtin_amdgcn_s_setprio(1);
#pragma unroll
        for (int kk = 0; kk < 4; kk++) {
#pragma unroll
            for (int j = 0; j < 4; j++) {
                int slot = (kk * 4 + quad) ^ (lrow & 7);
                short8 bk = *(const short8*)&Ks[cur][(j * 16 + lrow) * DH + slot * 8];
                sacc[0][j] = __builtin_amdgcn_mfma_f32_16x16x32_bf16(aq[0][kk], bk, sacc[0][j], 0, 0, 0);
                sacc[1][j] = __builtin_amdgcn_mfma_f32_16x16x32_bf16(aq[1][kk], bk, sacc[1][j], 0, 0, 0);
            }
        }
        __builtin_amdgcn_s_setprio(0);

#pragma unroll
        for (int h = 0; h < 2; h++) {
            if (k0 + ABK - 1 > qw + 16 * h) {
#pragma unroll
                for (int j = 0; j < 4; j++) {
                    int key = k0 + j * 16 + lrow;
#pragma unroll
                    for (int r = 0; r < 4; r++) {
                        int q = qw + 16 * h + quad * 4 + r;
                        if (key > q) sacc[h][j][r] = -1e30f;
                    }
                }
            }
        }

        // tile maxima (uniform across each 16-lane group after row_max16)
        float mt_[2][4];
#pragma unroll
        for (int h = 0; h < 2; h++)
#pragma unroll
            for (int r = 0; r < 4; r++) {
                float mt = fmaxf(fmaxf(sacc[h][0][r], sacc[h][1][r]),
                                 fmaxf(sacc[h][2][r], sacc[h][3][r]));
                mt_[h][r] = row_max16(mt);
            }
        // defer-max (T13): if no row's max grew by >8, keep old m (P<=e^8)
        bool defer = true;
#pragma unroll
        for (int h = 0; h < 2; h++)
#pragma unroll
            for (int r = 0; r < 4; r++)
                defer = defer && (mt_[h][r] - mrow[h][r] <= 8.0f);
        defer = __all(defer);

        float alpha[2][4];
        if (!defer) {
#pragma unroll
            for (int h = 0; h < 2; h++)
#pragma unroll
                for (int r = 0; r < 4; r++) {
                    float mn = fmaxf(mrow[h][r], mt_[h][r]);
                    alpha[h][r] = __expf(mrow[h][r] - mn);
                    mrow[h][r] = mn;
                }
        }

        // P = exp(S - m); parity-packed b32 Ps writes:
        // even lane writes (h=0, cols e,e+1), odd lane (h=1, cols e-1,e)
#pragma unroll
        for (int r = 0; r < 4; r++) {
            const int rp0 = quad * 4 + r;
            const int rowp = (lane & 1) ? (16 + rp0) : rp0;
            float rs0 = 0.f, rs1 = 0.f;
#pragma unroll
            for (int j = 0; j < 4; j++) {
                float p0 = __expf(sacc[0][j][r] - mrow[0][r]);
                float p1 = __expf(sacc[1][j][r] - mrow[1][r]);
                rs0 += p0; rs1 += p1;
                float n0 = dpp_movf<0xB1>(p0);   // neighbor (col xor 1)
                float n1 = dpp_movf<0xB1>(p1);
                unsigned pk = (lane & 1)
                    ? ((unsigned)f2bf(n1) | ((unsigned)f2bf(p1) << 16))
                    : ((unsigned)f2bf(p0) | ((unsigned)f2bf(n0) << 16));
                int slot = (2 * j + (lrow >> 3)) ^ (rp0 & 7);  // (16+rp0)&7==rp0&7
                *(unsigned*)&Ps[w][rowp][slot * 8 + (lrow & 6)] = pk;
            }
            rs0 = row_sum16(rs0); rs1 = row_sum16(rs1);
            if (defer) {
                lsum[0][r] += rs0;
                lsum[1][r] += rs1;
            } else {
                lsum[0][r] = lsum[0][r] * alpha[0][r] + rs0;
                lsum[1][r] = lsum[1][r] * alpha[1][r] + rs1;
            }
        }
        if (!defer) {
#pragma unroll
            for (int h = 0; h < 2; h++)
#pragma unroll
                for (int dt = 0; dt < 8; dt++)
#pragma unroll
                    for (int r = 0; r < 4; r++) oacc[h][dt][r] *= alpha[h][r];
        }

        __builtin_amdgcn_s_setprio(1);
#pragma unroll
        for (int kk2 = 0; kk2 < 2; kk2++) {
            int pslot = (kk2 * 4 + quad) ^ (lrow & 7);
            short8 pa0 = *(const short8*)&Ps[w][lrow][pslot * 8];
            short8 pa1 = *(const short8*)&Ps[w][16 + lrow][pslot * 8];
#pragma unroll
            for (int dt = 0; dt < 8; dt++) {
                int slot = (kk2 * 4 + quad) ^ (lrow & 7);
                short8 bv = *(const short8*)&Vs[cur][(dt * 16 + lrow) * ABK + slot * 8];
                oacc[0][dt] = __builtin_amdgcn_mfma_f32_16x16x32_bf16(pa0, bv, oacc[0][dt], 0, 0, 0);
                oacc[1][dt] = __builtin_amdgcn_mfma_f32_16x16x32_bf16(pa1, bv, oacc[1][dt], 0, 0, 0);
            }
        }
        __builtin_amdgcn_s_setprio(0);

        __syncthreads();
        cur ^= 1;
    }

    const int b = bh >> 4, hd = bh & 15;
#pragma unroll
    for (int h = 0; h < 2; h++)
#pragma unroll
        for (int r = 0; r < 4; r++) {
            float inv = 1.f / lsum[h][r];
            int q = qw + 16 * h + quad * 4 + r;
            size_t base = ((size_t)b * LL + q) * D + hd * DH;
#pragma unroll
            for (int dt = 0; dt < 8; dt++)
                AOb[base + dt * 16 + lrow] = f2bf(oacc[h][dt][r] * inv);
        }
}

// ---------------------------------------------------------------------------
extern "C" void kernel_launch(void* const* d_in, const int* in_sizes, int n_in,
                              void* d_out, int out_size, void* d_ws, size_t ws_size,
                              hipStream_t stream)
{
    const float* x     = (const float*)d_in[0];
    const float* w_qkv = (const float*)d_in[1];
    const float* w_out = (const float*)d_in[2];
    const float* s_qk  = (const float*)d_in[3];
    float* out = (float*)d_out;

    const size_t SZ = (size_t)BB * NH * LL * DH;   // 8388608 elements
    unsigned short* u = (unsigned short*)d_ws;
    unsigned short* xb    = u;                               // x bf16 -> later AO bf16
    unsigned short* wqkvT = xb    + (size_t)MROWS * KDIM;    // 6144 x 2048
    unsigned short* woutT = wqkvT + (size_t)(3 * D) * KDIM;  // 2048 x 2048
    unsigned short* Qb    = woutT + (size_t)D * KDIM;
    unsigned short* Kb    = Qb + SZ;
    unsigned short* VtG   = Kb + SZ;   // V written directly transposed here

    // 1) x -> bf16
    cast_bf16_r15<<<(MROWS * KDIM / 4 + 255) / 256, 256, 0, stream>>>(
        x, xb, MROWS * KDIM / 4);
    // 2) w_qkv -> (3D x K) bf16
    transpose_cast_r15<<<dim3(3 * D / 32, KDIM / 32), 256, 0, stream>>>(
        w_qkv, wqkvT, KDIM, 3 * D);
    // 3) QKV projection; Q/K scatter (B,H,L,Dh), V direct-transposed (bh,dh,l)
    gemm_mfma_r15<3 * D, 1><<<dim3(3 * D / 128, MROWS / 128), 256, 0, stream>>>(
        xb, wqkvT, nullptr, Qb, Kb, VtG);
    // 4) RoPE + normalize in place (+ s_qk into Q); one wave per row
    rope_norm_r15<<<dim3(BHD * LL / 4), 256, 0, stream>>>(Qb, Kb, s_qk);
    // 5) flash attention -> AO bf16 (B,L,D), reusing xb
    attn_mfma_r15<<<dim3(BHD, LL / ABQ), 256, 0, stream>>>(Qb, Kb, VtG, xb);
    // 6) w_out -> bf16
    transpose_cast_r15<<<dim3(D / 32, D / 32), 256, 0, stream>>>(
        w_out, woutT, D, D);
    // 7) output projection
    gemm_mfma_r15<D, 0><<<dim3(D / 128, MROWS / 128), 256, 0, stream>>>(
        xb, woutT, out, nullptr, nullptr, nullptr);
}

// Round 8
// 429.099 us; speedup vs baseline: 1.0581x; 1.0581x over previous
//
#include <hip/hip_runtime.h>
#include <math.h>

// Round 16: conservative recombination after round-15's confounded regression.
//  * GEMM: EXACT round-14 kernel (verified 127.8 us QKV, VGPR 72, FETCH 90MB).
//    Round-15's XCD stripe swizzle RAISED fetch to 123MB (natural x-fastest
//    order already gives each XCD a fixed resident B-slice: 48 n-tiles % 8
//    XCDs = 0) and the V-direct epilogue raised VGPR 72->124. Both reverted.
//  * transpose_v kernel restored.
//  * Attention: round-15 version kept (parity-packed Ps b32 writes +
//    defer-max T13) — measured ~neutral-positive, passed identically.
//  * RoPE+norm: round-14 wave-per-row version.

#define D 2048
#define NH 16
#define DH 128
#define BB 2
#define LL 2048
#define BHD (BB*NH)      // 32
#define MROWS (BB*LL)    // 4096
#define KDIM D

typedef __attribute__((ext_vector_type(8))) short short8;
typedef __attribute__((ext_vector_type(4))) float floatx4;

// fp32 -> bf16, round-to-nearest-even
__device__ __forceinline__ unsigned short f2bf(float f) {
    unsigned u = __float_as_uint(f);
    unsigned r = u + 0x7FFFu + ((u >> 16) & 1u);
    return (unsigned short)(r >> 16);
}
__device__ __forceinline__ float bf2f(unsigned short u) {
    return __uint_as_float(((unsigned)u) << 16);
}

// async global->LDS DMA (16 B per lane); LDS dest = wave-uniform base + lane*16
__device__ __forceinline__ void async16(const void* g, void* lds) {
    __builtin_amdgcn_global_load_lds(
        (const __attribute__((address_space(1))) unsigned int*)g,
        (__attribute__((address_space(3))) unsigned int*)lds, 16, 0, 0);
}

// DPP lane-moves within 16-lane rows (VALU pipe, avoids ds_bpermute).
template<int CTRL>
__device__ __forceinline__ float dpp_movf(float x) {
    return __int_as_float(__builtin_amdgcn_update_dpp(
        0, __float_as_int(x), CTRL, 0xF, 0xF, true));
}
__device__ __forceinline__ float row_max16(float x) {
    x = fmaxf(x, dpp_movf<0xB1>(x));    // quad_perm xor1
    x = fmaxf(x, dpp_movf<0x4E>(x));    // quad_perm xor2
    x = fmaxf(x, dpp_movf<0x124>(x));   // row_ror:4
    x = fmaxf(x, dpp_movf<0x128>(x));   // row_ror:8
    return x;
}
__device__ __forceinline__ float row_sum16(float x) {
    x += dpp_movf<0xB1>(x);
    x += dpp_movf<0x4E>(x);
    x += dpp_movf<0x124>(x);
    x += dpp_movf<0x128>(x);
    return x;
}

// ---------------------------------------------------------------------------
// elementwise fp32 -> bf16 cast (float4 vectorized)
// ---------------------------------------------------------------------------
__global__ __launch_bounds__(256)
void cast_bf16_r16(const float* __restrict__ in,
                   unsigned short* __restrict__ out, int n4)
{
    int i = blockIdx.x * 256 + threadIdx.x;
    if (i < n4) {
        float4 v = ((const float4*)in)[i];
        ushort4 o;
        o.x = f2bf(v.x); o.y = f2bf(v.y); o.z = f2bf(v.z); o.w = f2bf(v.w);
        ((ushort4*)out)[i] = o;
    }
}

// ---------------------------------------------------------------------------
// W (K x N fp32 row-major) -> Wt (N x K bf16 row-major) via 32x32 LDS tile
// ---------------------------------------------------------------------------
__global__ __launch_bounds__(256)
void transpose_cast_r16(const float* __restrict__ W,
                        unsigned short* __restrict__ Wt, int K, int N)
{
    __shared__ float tile[32][33];
    const int tx = threadIdx.x & 31, ty = threadIdx.x >> 5;  // ty: 0..7
    const int n0 = blockIdx.x * 32, k0 = blockIdx.y * 32;
#pragma unroll
    for (int r = 0; r < 4; r++)
        tile[ty + 8 * r][tx] = W[(size_t)(k0 + ty + 8 * r) * N + n0 + tx];
    __syncthreads();
#pragma unroll
    for (int r = 0; r < 4; r++)
        Wt[(size_t)(n0 + ty + 8 * r) * K + k0 + tx] = f2bf(tile[tx][ty + 8 * r]);
}

// ---------------------------------------------------------------------------
// V (bh, l, dh) -> Vt (bh, dh, l), bf16, 32x32 LDS tile (+2B pad per row)
// ---------------------------------------------------------------------------
__global__ __launch_bounds__(256)
void transpose_v_r16(const unsigned short* __restrict__ Vb,
                     unsigned short* __restrict__ VtG)
{
    __shared__ unsigned short tile[32][34];
    const int tx = threadIdx.x & 31, ty = threadIdx.x >> 5;
    const int l0 = blockIdx.x * 32, d0 = blockIdx.y * 32;
    const int bh = blockIdx.z;
    const unsigned short* src = Vb + (size_t)bh * LL * DH;
    unsigned short* dst = VtG + (size_t)bh * DH * LL;
#pragma unroll
    for (int r = 0; r < 4; r++)
        tile[ty + 8 * r][tx] = src[(size_t)(l0 + ty + 8 * r) * DH + d0 + tx];
    __syncthreads();
#pragma unroll
    for (int r = 0; r < 4; r++)
        dst[(size_t)(d0 + ty + 8 * r) * LL + l0 + tx] = tile[tx][ty + 8 * r];
}

// ---------------------------------------------------------------------------
// bf16 MFMA GEMM (m97 structure): C(MxN) = A(MxK) * Bt(NxK)^T.
// 128x128 block tile, BK=32, 4 waves each owning a 64x64 quadrant.
// MODE 0: fp32 store to C. MODE 1: bf16 scatter into Q/K/V (B,H,L,Dh).
// Natural blockIdx mapping (x = n-tile fastest): each XCD keeps a fixed
// resident B n-slice in its L2 (48 % 8 == 0) — do not "optimize" this.
// ---------------------------------------------------------------------------
template<int N, int MODE>
__global__ __launch_bounds__(256)
void gemm_mfma_r16(const unsigned short* __restrict__ A,
                   const unsigned short* __restrict__ Bt,
                   float* __restrict__ C, unsigned short* __restrict__ Qo,
                   unsigned short* __restrict__ Ko, unsigned short* __restrict__ Vo)
{
    __shared__ unsigned short As[128 * 32];   // [m][k] contiguous (DMA order)
    __shared__ unsigned short Bs[128 * 32];   // [n][k] contiguous
    const int t = threadIdx.x;
    const int w = t >> 6, lane = t & 63;
    const int lrow = lane & 15, quad = lane >> 4;
    const int m0 = blockIdx.y * 128, n0 = blockIdx.x * 128;
    const int wm = (w >> 1) * 64, wn = (w & 1) * 64;

    floatx4 acc[4][4];
#pragma unroll
    for (int i = 0; i < 4; i++)
#pragma unroll
        for (int j = 0; j < 4; j++) acc[i][j] = (floatx4){0.f, 0.f, 0.f, 0.f};

    const int srow = 32 * w + (lane >> 2);
    const int sseg = (lane & 3) * 8;

    for (int k0 = 0; k0 < KDIM; k0 += 32) {
        __syncthreads();
        async16(&A [(size_t)(m0 + srow)      * KDIM + k0 + sseg], &As[(32 * w)      * 32]);
        async16(&A [(size_t)(m0 + srow + 16) * KDIM + k0 + sseg], &As[(32 * w + 16) * 32]);
        async16(&Bt[(size_t)(n0 + srow)      * KDIM + k0 + sseg], &Bs[(32 * w)      * 32]);
        async16(&Bt[(size_t)(n0 + srow + 16) * KDIM + k0 + sseg], &Bs[(32 * w + 16) * 32]);
        __syncthreads();

        short8 a[4], b[4];
#pragma unroll
        for (int i = 0; i < 4; i++)
            a[i] = *(const short8*)&As[(wm + i * 16 + lrow) * 32 + quad * 8];
#pragma unroll
        for (int j = 0; j < 4; j++)
            b[j] = *(const short8*)&Bs[(wn + j * 16 + lrow) * 32 + quad * 8];
#pragma unroll
        for (int i = 0; i < 4; i++)
#pragma unroll
            for (int j = 0; j < 4; j++)
                acc[i][j] = __builtin_amdgcn_mfma_f32_16x16x32_bf16(a[i], b[j], acc[i][j], 0, 0, 0);
    }

    // C/D fragment layout: col = lane&15, row = quad*4 + reg (m89-verified)
    if (MODE == 0) {
#pragma unroll
        for (int i = 0; i < 4; i++)
#pragma unroll
            for (int j = 0; j < 4; j++) {
                int col = n0 + wn + j * 16 + lrow;
#pragma unroll
                for (int r = 0; r < 4; r++) {
                    int m = m0 + wm + i * 16 + quad * 4 + r;
                    C[(size_t)m * N + col] = acc[i][j][r];
                }
            }
    } else {
        const int s = n0 >> 11;              // qkv slot (uniform per block)
        const int h = (n0 & 2047) >> 7;
        unsigned short* dst = (s == 0) ? Qo : (s == 1) ? Ko : Vo;
#pragma unroll
        for (int i = 0; i < 4; i++)
#pragma unroll
            for (int j = 0; j < 4; j++) {
                int dh = wn + j * 16 + lrow;
#pragma unroll
                for (int r = 0; r < 4; r++) {
                    int m = m0 + wm + i * 16 + quad * 4 + r;
                    int b = m >> 11, l = m & 2047;
                    dst[(((size_t)b * NH + h) * LL + l) * DH + dh] = f2bf(acc[i][j][r]);
                }
            }
    }
}

// ---------------------------------------------------------------------------
// RoPE + L2-normalize: one 64-lane wave per (bh,l) row, Q and K together.
// Rotate pair (d, d+64) shares cos/sin; zero LDS, zero barriers.
// ---------------------------------------------------------------------------
__global__ __launch_bounds__(256)
void rope_norm_r16(unsigned short* __restrict__ Q,
                   unsigned short* __restrict__ K,
                   const float* __restrict__ s_qk_ptr)
{
    const int wid  = threadIdx.x >> 6;
    const int lane = threadIdx.x & 63;
    const int row  = blockIdx.x * 4 + wid;       // flattened (bh*LL + l)
    const int l    = row & (LL - 1);
    const size_t base = (size_t)row * DH;

    // inv_freq = 10000^(-lane/64); ln(10000)/64 = 0.14391156831
    float ang = (float)l * expf(-0.14391157f * (float)lane);
    float c = cosf(ang), s = sinf(ang);

    float qlo = bf2f(Q[base + lane]), qhi = bf2f(Q[base + lane + 64]);
    float klo = bf2f(K[base + lane]), khi = bf2f(K[base + lane + 64]);

    float qr_lo = fmaf(qlo, c, (-qhi) * s);
    float qr_hi = fmaf(qhi, c,   qlo  * s);
    float kr_lo = fmaf(klo, c, (-khi) * s);
    float kr_hi = fmaf(khi, c,   klo  * s);

    float qs = qr_lo * qr_lo + qr_hi * qr_hi;
    float ks = kr_lo * kr_lo + kr_hi * kr_hi;
    qs = row_sum16(qs);  ks = row_sum16(ks);
    qs += __shfl_xor(qs, 16);  ks += __shfl_xor(ks, 16);
    qs += __shfl_xor(qs, 32);  ks += __shfl_xor(ks, 32);
    float qn = fmaxf(sqrtf(qs), 1e-12f);
    float kn = fmaxf(sqrtf(ks), 1e-12f);

    float sqk = s_qk_ptr[0];
    Q[base + lane]      = f2bf(qr_lo / qn * sqk);
    Q[base + lane + 64] = f2bf(qr_hi / qn * sqk);
    K[base + lane]      = f2bf(kr_lo / kn);
    K[base + lane + 64] = f2bf(kr_hi / kn);
}

// ---------------------------------------------------------------------------
// bf16 MFMA flash attention, causal. BQ=128 per block (4 waves x 32 q-rows),
// BK=64. K/V double-buffered via async DMA with XOR-swizzled layouts; each
// Ks/Vs ds_read_b128 feeds two MFMAs; DPP softmax; 80 KB LDS.
// Parity-packed Ps b32 writes + defer-max (T13, THR=8).
// ---------------------------------------------------------------------------
#define ABQ 128
#define ABK 64
__global__ __launch_bounds__(256, 2)
void attn_mfma_r16(const unsigned short* __restrict__ Q,
                   const unsigned short* __restrict__ K,
                   const unsigned short* __restrict__ Vt,
                   unsigned short* __restrict__ AOb)
{
    __shared__ __align__(16) unsigned short Ks[2][ABK * DH];   // 32 KB
    __shared__ __align__(16) unsigned short Vs[2][DH * ABK];   // 32 KB
    __shared__ __align__(16) unsigned short Ps[4][32][64];     // 16 KB swizzled

    const int t = threadIdx.x;
    const int w = t >> 6, lane = t & 63;
    const int lrow = lane & 15, quad = lane >> 4;
    const int bh = blockIdx.x;
    const int y  = blockIdx.y;
    const int qt = (y < 8) ? (15 - y) : (y - 8);   // heavy+light pairing
    const int q0 = qt * ABQ;
    const int qw = q0 + w * 32;                    // wave's first q-row

    const unsigned short* Qb = Q  + (size_t)bh * LL * DH;
    const unsigned short* Kb = K  + (size_t)bh * LL * DH;
    const unsigned short* Vg = Vt + (size_t)bh * DH * LL;

    short8 aq[2][4];
#pragma unroll
    for (int h = 0; h < 2; h++)
#pragma unroll
        for (int kk = 0; kk < 4; kk++)
            aq[h][kk] = *(const short8*)&Qb[(size_t)(qw + 16 * h + lrow) * DH
                                            + kk * 32 + quad * 8];

    floatx4 oacc[2][8];
#pragma unroll
    for (int h = 0; h < 2; h++)
#pragma unroll
        for (int dt = 0; dt < 8; dt++) oacc[h][dt] = (floatx4){0.f, 0.f, 0.f, 0.f};
    float mrow[2][4], lsum[2][4];
#pragma unroll
    for (int h = 0; h < 2; h++)
#pragma unroll
        for (int r = 0; r < 4; r++) { mrow[h][r] = -1e30f; lsum[h][r] = 0.f; }

    auto STAGE = [&](int tile, int buf) {
        const int k0s = tile * ABK;
#pragma unroll
        for (int c = 0; c < 4; c++) {
            int row = 16 * w + 4 * c;
            int r   = row + (lane >> 4);
            int col = (lane & 15) ^ (r & 7);
            async16(&Kb[(size_t)(k0s + r) * DH + col * 8], &Ks[buf][row * DH]);
        }
#pragma unroll
        for (int c = 0; c < 4; c++) {
            int row = 32 * w + 8 * c;
            int r   = row + (lane >> 3);
            int col = (lane & 7) ^ (r & 7);
            async16(&Vg[(size_t)r * LL + k0s + col * 8], &Vs[buf][row * ABK]);
        }
    };

    const int ntiles = 2 * qt + 2;
    STAGE(0, 0);
    __syncthreads();

    int cur = 0;
    for (int tile = 0; tile < ntiles; tile++) {
        const int k0 = tile * ABK;
        if (tile + 1 < ntiles) STAGE(tile + 1, cur ^ 1);

        floatx4 sacc[2][4];
#pragma unroll
        for (int h = 0; h < 2; h++)
#pragma unroll
            for (int j = 0; j < 4; j++) sacc[h][j] = (floatx4){0.f, 0.f, 0.f, 0.f};
        __builtin_amdgcn_s_setprio(1);
#pragma unroll
        for (int kk = 0; kk < 4; kk++) {
#pragma unroll
            for (int j = 0; j < 4; j++) {
                int slot = (kk * 4 + quad) ^ (lrow & 7);
                short8 bk = *(const short8*)&Ks[cur][(j * 16 + lrow) * DH + slot * 8];
                sacc[0][j] = __builtin_amdgcn_mfma_f32_16x16x32_bf16(aq[0][kk], bk, sacc[0][j], 0, 0, 0);
                sacc[1][j] = __builtin_amdgcn_mfma_f32_16x16x32_bf16(aq[1][kk], bk, sacc[1][j], 0, 0, 0);
            }
        }
        __builtin_amdgcn_s_setprio(0);

#pragma unroll
        for (int h = 0; h < 2; h++) {
            if (k0 + ABK - 1 > qw + 16 * h) {
#pragma unroll
                for (int j = 0; j < 4; j++) {
                    int key = k0 + j * 16 + lrow;
#pragma unroll
                    for (int r = 0; r < 4; r++) {
                        int q = qw + 16 * h + quad * 4 + r;
                        if (key > q) sacc[h][j][r] = -1e30f;
                    }
                }
            }
        }

        // tile maxima (uniform across each 16-lane group after row_max16)
        float mt_[2][4];
#pragma unroll
        for (int h = 0; h < 2; h++)
#pragma unroll
            for (int r = 0; r < 4; r++) {
                float mt = fmaxf(fmaxf(sacc[h][0][r], sacc[h][1][r]),
                                 fmaxf(sacc[h][2][r], sacc[h][3][r]));
                mt_[h][r] = row_max16(mt);
            }
        // defer-max (T13): if no row's max grew by >8, keep old m (P<=e^8)
        bool defer = true;
#pragma unroll
        for (int h = 0; h < 2; h++)
#pragma unroll
            for (int r = 0; r < 4; r++)
                defer = defer && (mt_[h][r] - mrow[h][r] <= 8.0f);
        defer = __all(defer);

        float alpha[2][4];
        if (!defer) {
#pragma unroll
            for (int h = 0; h < 2; h++)
#pragma unroll
                for (int r = 0; r < 4; r++) {
                    float mn = fmaxf(mrow[h][r], mt_[h][r]);
                    alpha[h][r] = __expf(mrow[h][r] - mn);
                    mrow[h][r] = mn;
                }
        }

        // P = exp(S - m); parity-packed b32 Ps writes:
        // even lane writes (h=0, cols e,e+1), odd lane (h=1, cols e-1,e)
#pragma unroll
        for (int r = 0; r < 4; r++) {
            const int rp0 = quad * 4 + r;
            const int rowp = (lane & 1) ? (16 + rp0) : rp0;
            float rs0 = 0.f, rs1 = 0.f;
#pragma unroll
            for (int j = 0; j < 4; j++) {
                float p0 = __expf(sacc[0][j][r] - mrow[0][r]);
                float p1 = __expf(sacc[1][j][r] - mrow[1][r]);
                rs0 += p0; rs1 += p1;
                float n0 = dpp_movf<0xB1>(p0);   // neighbor (col xor 1)
                float n1 = dpp_movf<0xB1>(p1);
                unsigned pk = (lane & 1)
                    ? ((unsigned)f2bf(n1) | ((unsigned)f2bf(p1) << 16))
                    : ((unsigned)f2bf(p0) | ((unsigned)f2bf(n0) << 16));
                int slot = (2 * j + (lrow >> 3)) ^ (rp0 & 7);  // (16+rp0)&7==rp0&7
                *(unsigned*)&Ps[w][rowp][slot * 8 + (lrow & 6)] = pk;
            }
            rs0 = row_sum16(rs0); rs1 = row_sum16(rs1);
            if (defer) {
                lsum[0][r] += rs0;
                lsum[1][r] += rs1;
            } else {
                lsum[0][r] = lsum[0][r] * alpha[0][r] + rs0;
                lsum[1][r] = lsum[1][r] * alpha[1][r] + rs1;
            }
        }
        if (!defer) {
#pragma unroll
            for (int h = 0; h < 2; h++)
#pragma unroll
                for (int dt = 0; dt < 8; dt++)
#pragma unroll
                    for (int r = 0; r < 4; r++) oacc[h][dt][r] *= alpha[h][r];
        }

        __builtin_amdgcn_s_setprio(1);
#pragma unroll
        for (int kk2 = 0; kk2 < 2; kk2++) {
            int pslot = (kk2 * 4 + quad) ^ (lrow & 7);
            short8 pa0 = *(const short8*)&Ps[w][lrow][pslot * 8];
            short8 pa1 = *(const short8*)&Ps[w][16 + lrow][pslot * 8];
#pragma unroll
            for (int dt = 0; dt < 8; dt++) {
                int slot = (kk2 * 4 + quad) ^ (lrow & 7);
                short8 bv = *(const short8*)&Vs[cur][(dt * 16 + lrow) * ABK + slot * 8];
                oacc[0][dt] = __builtin_amdgcn_mfma_f32_16x16x32_bf16(pa0, bv, oacc[0][dt], 0, 0, 0);
                oacc[1][dt] = __builtin_amdgcn_mfma_f32_16x16x32_bf16(pa1, bv, oacc[1][dt], 0, 0, 0);
            }
        }
        __builtin_amdgcn_s_setprio(0);

        __syncthreads();
        cur ^= 1;
    }

    const int b = bh >> 4, hd = bh & 15;
#pragma unroll
    for (int h = 0; h < 2; h++)
#pragma unroll
        for (int r = 0; r < 4; r++) {
            float inv = 1.f / lsum[h][r];
            int q = qw + 16 * h + quad * 4 + r;
            size_t base = ((size_t)b * LL + q) * D + hd * DH;
#pragma unroll
            for (int dt = 0; dt < 8; dt++)
                AOb[base + dt * 16 + lrow] = f2bf(oacc[h][dt][r] * inv);
        }
}

// ---------------------------------------------------------------------------
extern "C" void kernel_launch(void* const* d_in, const int* in_sizes, int n_in,
                              void* d_out, int out_size, void* d_ws, size_t ws_size,
                              hipStream_t stream)
{
    const float* x     = (const float*)d_in[0];
    const float* w_qkv = (const float*)d_in[1];
    const float* w_out = (const float*)d_in[2];
    const float* s_qk  = (const float*)d_in[3];
    float* out = (float*)d_out;

    const size_t SZ = (size_t)BB * NH * LL * DH;   // 8388608 elements
    unsigned short* u = (unsigned short*)d_ws;
    unsigned short* xb    = u;                               // x bf16 -> later AO bf16
    unsigned short* wqkvT = xb    + (size_t)MROWS * KDIM;    // 6144 x 2048
    unsigned short* woutT = wqkvT + (size_t)(3 * D) * KDIM;  // 2048 x 2048
    unsigned short* Qb    = woutT + (size_t)D * KDIM;
    unsigned short* Kb    = Qb + SZ;
    unsigned short* Vb    = Kb + SZ;
    unsigned short* VtG   = Vb + SZ;

    // 1) x -> bf16
    cast_bf16_r16<<<(MROWS * KDIM / 4 + 255) / 256, 256, 0, stream>>>(
        x, xb, MROWS * KDIM / 4);
    // 2) w_qkv -> (3D x K) bf16
    transpose_cast_r16<<<dim3(3 * D / 32, KDIM / 32), 256, 0, stream>>>(
        w_qkv, wqkvT, KDIM, 3 * D);
    // 3) QKV projection, bf16 scatter into (B,H,L,Dh)
    gemm_mfma_r16<3 * D, 1><<<dim3(3 * D / 128, MROWS / 128), 256, 0, stream>>>(
        xb, wqkvT, nullptr, Qb, Kb, Vb);
    // 4) RoPE + normalize in place (+ s_qk into Q); one wave per row
    rope_norm_r16<<<dim3(BHD * LL / 4), 256, 0, stream>>>(Qb, Kb, s_qk);
    // 5) V -> V^T (bh, dh, l)
    transpose_v_r16<<<dim3(LL / 32, DH / 32, BHD), 256, 0, stream>>>(Vb, VtG);
    // 6) flash attention -> AO bf16 (B,L,D), reusing xb
    attn_mfma_r16<<<dim3(BHD, LL / ABQ), 256, 0, stream>>>(Qb, Kb, VtG, xb);
    // 7) w_out -> bf16
    transpose_cast_r16<<<dim3(D / 32, D / 32), 256, 0, stream>>>(
        w_out, woutT, D, D);
    // 8) output projection
    gemm_mfma_r16<D, 0><<<dim3(D / 128, MROWS / 128), 256, 0, stream>>>(
        xb, woutT, out, nullptr, nullptr, nullptr);
}